// Round 3
// baseline (83.548 us; speedup 1.0000x reference)
//
#include <hip/hip_runtime.h>
#include <math.h>

#define BB 32
#define NN 2048
#define TB 256            // k1/k2 threads
#define QT 8              // queries per thread in k1 -> 2048 = NN per block
#define RCH 16            // ref chunks (split of the min over refs)
#define MCH (NN / RCH)    // 128 refs per chunk

// ws layout: part[RCH][2*BB][NN] f32 (8 MB) | bacc[BB][7] f32 (896 B) | cnt[BB] int (128 B)
// bacc+cnt = exactly 256 words, zeroed by k1 block (0,0,0); k1->k2 dispatch
// boundary is the release fence (no device-scope threadfence: costs ~100us).

__device__ __forceinline__ float wred(float v) {
#pragma unroll
    for (int o = 32; o > 0; o >>= 1) v += __shfl_down(v, o, 64);
    return v;
}

// K1: grid (1, BB, 2*RCH); blockIdx.z = rc*2 + role. 1024 blocks = 4/CU exact,
// 256 threads = 4 waves/SIMD (R2 showed 2 waves/SIMD costs ~2.3us).
// Partial min over one 128-ref chunk for all 2048 queries of (b, role).
// Thread owns 8 CONTIGUOUS queries: loads = 6 coalesced dwordx4, stores = 2 dwordx4.
__global__ __launch_bounds__(TB) void k1_chamfer(
    const float* __restrict__ pred, const float* __restrict__ tgt,
    float* __restrict__ part, int* __restrict__ zero_region,
    float* __restrict__ out)
{
    __shared__ float sa[MCH], sb[MCH], sc[MCH];

    const int tid  = threadIdx.x;
    const int b    = blockIdx.y;
    const int role = blockIdx.z & 1;
    const int rc   = blockIdx.z >> 1;

    // Block (0,0): zero bacc[32][7]+cnt[32] (256 words) and out[0..3].
    if (b == 0 && blockIdx.z == 0) {
        zero_region[tid] = 0;
        if (tid < 4) out[tid] = 0.0f;
    }

    const float* q = role ? tgt : pred;
    const float* r = role ? pred : tgt;

    // Query micro-panel first (independent of LDS stage; hides under barrier).
    const float* qb_ = q + (size_t)b * NN * 3;
    float f[3 * QT];
    const float4* qv = (const float4*)(qb_ + (size_t)tid * (QT * 3));
#pragma unroll
    for (int i = 0; i < 3 * QT / 4; i++) ((float4*)f)[i] = qv[i];

    float px[QT], py[QT], mn[QT];
#pragma unroll
    for (int j = 0; j < QT; j++) {
        px[j] = f[3 * j + 0];
        py[j] = f[3 * j + 1];
        mn[j] = 3.4e38f;
    }

    // Stage refs in norm form; invisible refs poisoned far (d2 ~ 2e18).
    if (tid < MCH) {
        const float* rb = r + ((size_t)b * NN + (size_t)rc * MCH) * 3;
        float rx = rb[3 * tid + 0];
        float ry = rb[3 * tid + 1];
        float rv = rb[3 * tid + 2];
        if (rv != 1.0f) { rx = 1.0e9f; ry = 1.0e9f; }
        sa[tid] = -2.0f * rx;
        sb[tid] = -2.0f * ry;
        sc[tid] = fmaf(rx, rx, ry * ry);
    }
    __syncthreads();

    // 8 refs/iter: 6 uniform ds_read_b128 (broadcast, conflict-free),
    // per query 16 fma + 4 v_min3 -> 2.5 VALU/pair.
#pragma unroll 2
    for (int m = 0; m < MCH; m += 8) {
        float4 a0 = *(const float4*)&sa[m], a1 = *(const float4*)&sa[m + 4];
        float4 b0 = *(const float4*)&sb[m], b1 = *(const float4*)&sb[m + 4];
        float4 c0 = *(const float4*)&sc[m], c1 = *(const float4*)&sc[m + 4];
#pragma unroll
        for (int j = 0; j < QT; j++) {
            float s0 = fmaf(px[j], a0.x, fmaf(py[j], b0.x, c0.x));
            float s1 = fmaf(px[j], a0.y, fmaf(py[j], b0.y, c0.y));
            float s2 = fmaf(px[j], a0.z, fmaf(py[j], b0.z, c0.z));
            float s3 = fmaf(px[j], a0.w, fmaf(py[j], b0.w, c0.w));
            float s4 = fmaf(px[j], a1.x, fmaf(py[j], b1.x, c1.x));
            float s5 = fmaf(px[j], a1.y, fmaf(py[j], b1.y, c1.y));
            float s6 = fmaf(px[j], a1.z, fmaf(py[j], b1.z, c1.z));
            float s7 = fmaf(px[j], a1.w, fmaf(py[j], b1.w, c1.w));
            float u = fminf(fminf(s0, s1), s2);
            float v = fminf(fminf(s3, s4), s5);
            float w = fminf(fminf(s6, s7), mn[j]);
            mn[j] = fminf(fminf(u, v), w);
        }
    }

    float o[QT];
#pragma unroll
    for (int j = 0; j < QT; j++)
        o[j] = fmaf(px[j], px[j], py[j] * py[j]) + mn[j];

    float4* po = (float4*)&part[((size_t)rc * (2 * BB) + (size_t)role * BB + b) * NN
                                + (size_t)tid * QT];
    po[0] = make_float4(o[0], o[1], o[2], o[3]);
    po[1] = make_float4(o[4], o[5], o[6], o[7]);
}

// K2: grid (NN/TB=8, BB) = 256 blocks (1/CU), 256 threads. Block (c,b) owns
// queries c*256..+256 of batch b, BOTH roles: combine 16 planes per query,
// sqrt+mask epilogue, block-reduce 7 sums. The LAST block per batch (atomic
// ticket) reads the batch sums back (atomic reads = device-coherent), does
// the nonlinear chamfer math, and atomicAdds the output terms. No k2b launch.
__global__ __launch_bounds__(TB) void k2_final(
    const float* __restrict__ pred, const float* __restrict__ tgt,
    const float* __restrict__ smask, const float* __restrict__ part,
    float* __restrict__ bacc, int* __restrict__ cnt, float* __restrict__ out)
{
    __shared__ float sred[7][4];
    const int tid = threadIdx.x;
    const int c   = blockIdx.x;
    const int b   = blockIdx.y;
    const int qi  = c * TB + tid;

    // Issue the small input loads early, then the 32 plane loads (interleaved
    // roles for MLP); all independent -> deep load queue at 1 wave/SIMD.
    const float* qp = pred + ((size_t)b * NN + qi) * 3;
    const float* tp = tgt  + ((size_t)b * NN + qi) * 3;
    const float2 sm = *(const float2*)&smask[((size_t)b * NN + qi) * 2];
    float qpx = qp[0], qpy = qp[1], qpv = qp[2];
    float tpx = tp[0], tpy = tp[1], tpv = tp[2];

    float m0 = 3.4e38f, m1 = 3.4e38f;
#pragma unroll
    for (int k = 0; k < RCH; k++) {
        m0 = fminf(m0, part[((size_t)k * (2 * BB) + b) * NN + qi]);
        m1 = fminf(m1, part[((size_t)k * (2 * BB) + BB + b) * NN + qi]);
    }

    float pvf = (qpv == 1.0f) ? 1.0f : 0.0f;     // pred visible
    float vm  = (tpv == 1.0f) ? 1.0f : 0.0f;     // tgt visible

    float a0 = sqrtf(fmaxf(m0, 1e-12f)) * pvf;   // contrib_p
    float a1 = pvf;                              // cnt_p
    float dx = qpx - tpx, dy = qpy - tpy;
    float e2 = fmaf(dx, dx, dy * dy);
    float tm = fminf(fmaxf(sm.x + sm.y, 0.0f), 1.0f) * vm;
    float a2 = e2 * vm;                          // point sum
    float a3 = e2 * tm;                          // struct sum
    float a4 = tm;                               // mask sum (parity with ref)
    float a5 = sqrtf(fmaxf(m1, 1e-12f)) * vm;    // contrib_t (query = tgt)
    float a6 = vm;                               // cnt_t

    float v[7] = {a0, a1, a2, a3, a4, a5, a6};
    const int wave = tid >> 6, lane = tid & 63;
#pragma unroll
    for (int i = 0; i < 7; i++) {
        float rv = wred(v[i]);
        if (lane == 0) sred[i][wave] = rv;
    }
    __syncthreads();

    if (tid == 0) {
        float s[7];
#pragma unroll
        for (int i = 0; i < 7; i++) {
            s[i] = sred[i][0] + sred[i][1] + sred[i][2] + sred[i][3];
            atomicAdd(&bacc[b * 7 + i], s[i]);   // device-scope, L2-coherent
        }
        // Order the 7 sum-atomics before the ticket: wait for their acks.
        asm volatile("s_waitcnt vmcnt(0)" ::: "memory");
        int old = atomicAdd(&cnt[b], 1);
        if (old == 7) {
            // All 8 chunk-blocks' sums complete (each ticketed after vmcnt(0)).
            float t[7];
#pragma unroll
            for (int i = 0; i < 7; i++)
                t[i] = atomicAdd(&bacc[b * 7 + i], 0.0f);  // coherent read
            float sp = t[0], cp = t[1], spt = t[2], sst = t[3];
            float st_ = t[5], ct = t[6];
            float mp = sp / fmaxf(cp, 1.0f);
            float mt = st_ / fmaxf(ct, 1.0f);
            float ch = (cp > 0.0f && ct > 0.0f) ? 0.5f * (mp + mt) : 0.0f;

            const float denom = (float)BB * (float)NN * 2.0f;
            float lp = spt / denom;          // loss_point contribution (batch b)
            float ls = sst / denom;          // loss_struct contribution
            float lc = ch / (float)BB;       // loss_chamfer contribution

            atomicAdd(&out[0], lp + 5.0f * lc + 2.0f * ls);
            atomicAdd(&out[1], lp);
            atomicAdd(&out[3], lc);
            // out[2] stays 0 (zeroed by k1)
        }
    }
}

extern "C" void kernel_launch(void* const* d_in, const int* in_sizes, int n_in,
                              void* d_out, int out_size, void* d_ws, size_t ws_size,
                              hipStream_t stream)
{
    const float* pred  = (const float*)d_in[0];
    const float* tgt   = (const float*)d_in[1];
    const float* smask = (const float*)d_in[2];
    float* out = (float*)d_out;
    float* part = (float*)d_ws;                                        // 8 MB
    float* bacc = (float*)((char*)d_ws + (size_t)RCH * 2 * BB * NN * 4); // 896 B
    int*   cnt  = (int*)(bacc + BB * 7);                               // 128 B

    k1_chamfer<<<dim3(1, BB, 2 * RCH), TB, 0, stream>>>(pred, tgt, part, (int*)bacc, out);
    k2_final<<<dim3(NN / TB, BB), TB, 0, stream>>>(pred, tgt, smask, part, bacc, cnt, out);
}

// Round 4
// 80.287 us; speedup vs baseline: 1.0406x; 1.0406x over previous
//
#include <hip/hip_runtime.h>
#include <math.h>

#define BB 32
#define NN 2048
#define TB 256            // k1/k2 threads
#define QT 8              // queries per thread in k1 -> 2048 = NN per block
#define RCH 16            // ref chunks (split of the min over refs)
#define MCH (NN / RCH)    // 128 refs per chunk

// ws layout: part[RCH][2*BB][NN] f32 (8 MB) | bacc[BB][7] f32 (896 B) | cnt[BB] int (128 B)
// bacc+cnt = exactly 256 words, zeroed by k1 block (0,0); the k1->k2 dispatch
// boundary is the release fence (no device-scope threadfence: costs ~100us).

__device__ __forceinline__ float wred(float v) {
#pragma unroll
    for (int o = 32; o > 0; o >>= 1) v += __shfl_down(v, o, 64);
    return v;
}

// K1: grid (1, BB, 2*RCH); blockIdx.z = rc*2 + role. 1024 blocks = 4/CU exact,
// 256 threads = 4 waves/SIMD (R2: dropping to 2 waves/SIMD cost ~2.3us).
// Partial min over one 128-ref chunk for all 2048 queries of (b, role).
// Thread owns 8 CONTIGUOUS queries: loads = 6 coalesced dwordx4, stores = 2 dwordx4.
__global__ __launch_bounds__(TB) void k1_chamfer(
    const float* __restrict__ pred, const float* __restrict__ tgt,
    float* __restrict__ part, int* __restrict__ zero_region,
    float* __restrict__ out)
{
    __shared__ float sa[MCH], sb[MCH], sc[MCH];

    const int tid  = threadIdx.x;
    const int b    = blockIdx.y;
    const int role = blockIdx.z & 1;
    const int rc   = blockIdx.z >> 1;

    // Block (0,0): zero bacc[32][7]+cnt[32] (256 words) and out[0..3].
    if (b == 0 && blockIdx.z == 0) {
        zero_region[tid] = 0;
        if (tid < 4) out[tid] = 0.0f;
    }

    const float* q = role ? tgt : pred;
    const float* r = role ? pred : tgt;

    // Query micro-panel first (independent of LDS stage; hides under barrier).
    const float* qb_ = q + (size_t)b * NN * 3;
    float f[3 * QT];
    const float4* qv = (const float4*)(qb_ + (size_t)tid * (QT * 3));
#pragma unroll
    for (int i = 0; i < 3 * QT / 4; i++) ((float4*)f)[i] = qv[i];

    float px[QT], py[QT], mn[QT];
#pragma unroll
    for (int j = 0; j < QT; j++) {
        px[j] = f[3 * j + 0];
        py[j] = f[3 * j + 1];
        mn[j] = 3.4e38f;
    }

    // Stage refs in norm form; invisible refs poisoned far (d2 ~ 2e18).
    if (tid < MCH) {
        const float* rb = r + ((size_t)b * NN + (size_t)rc * MCH) * 3;
        float rx = rb[3 * tid + 0];
        float ry = rb[3 * tid + 1];
        float rv = rb[3 * tid + 2];
        if (rv != 1.0f) { rx = 1.0e9f; ry = 1.0e9f; }
        sa[tid] = -2.0f * rx;
        sb[tid] = -2.0f * ry;
        sc[tid] = fmaf(rx, rx, ry * ry);
    }
    __syncthreads();

    // 8 refs/iter: 6 uniform ds_read_b128 (broadcast, conflict-free),
    // per query 16 fma + 4 v_min3 -> 2.5 VALU/pair.
#pragma unroll 2
    for (int m = 0; m < MCH; m += 8) {
        float4 a0 = *(const float4*)&sa[m], a1 = *(const float4*)&sa[m + 4];
        float4 b0 = *(const float4*)&sb[m], b1 = *(const float4*)&sb[m + 4];
        float4 c0 = *(const float4*)&sc[m], c1 = *(const float4*)&sc[m + 4];
#pragma unroll
        for (int j = 0; j < QT; j++) {
            float s0 = fmaf(px[j], a0.x, fmaf(py[j], b0.x, c0.x));
            float s1 = fmaf(px[j], a0.y, fmaf(py[j], b0.y, c0.y));
            float s2 = fmaf(px[j], a0.z, fmaf(py[j], b0.z, c0.z));
            float s3 = fmaf(px[j], a0.w, fmaf(py[j], b0.w, c0.w));
            float s4 = fmaf(px[j], a1.x, fmaf(py[j], b1.x, c1.x));
            float s5 = fmaf(px[j], a1.y, fmaf(py[j], b1.y, c1.y));
            float s6 = fmaf(px[j], a1.z, fmaf(py[j], b1.z, c1.z));
            float s7 = fmaf(px[j], a1.w, fmaf(py[j], b1.w, c1.w));
            float u = fminf(fminf(s0, s1), s2);
            float v = fminf(fminf(s3, s4), s5);
            float w = fminf(fminf(s6, s7), mn[j]);
            mn[j] = fminf(fminf(u, v), w);
        }
    }

    float o[QT];
#pragma unroll
    for (int j = 0; j < QT; j++)
        o[j] = fmaf(px[j], px[j], py[j] * py[j]) + mn[j];

    float4* po = (float4*)&part[((size_t)rc * (2 * BB) + (size_t)role * BB + b) * NN
                                + (size_t)tid * QT];
    po[0] = make_float4(o[0], o[1], o[2], o[3]);
    po[1] = make_float4(o[4], o[5], o[6], o[7]);
}

// K2: grid (NN/TB=8, BB) = 256 blocks (1/CU), 256 threads. Block (c,b) owns
// queries c*256..+256 of batch b, BOTH roles: combine 16 planes per query,
// sqrt+mask epilogue, block-reduce 7 sums. Lanes 0-6 of wave 0 issue the 7
// batch-sum atomics IN PARALLEL (one round-trip, not R3's serial chain),
// vmcnt(0) release, then the last block per batch (atomic ticket) gathers the
// batch sums (parallel atomic reads + shuffles) and writes the output terms.
__global__ __launch_bounds__(TB) void k2_final(
    const float* __restrict__ pred, const float* __restrict__ tgt,
    const float* __restrict__ smask, const float* __restrict__ part,
    float* __restrict__ bacc, int* __restrict__ cnt, float* __restrict__ out)
{
    __shared__ float sred[7][4];
    const int tid = threadIdx.x;
    const int c   = blockIdx.x;
    const int b   = blockIdx.y;
    const int qi  = c * TB + tid;

    const float* qp = pred + ((size_t)b * NN + qi) * 3;
    const float* tp = tgt  + ((size_t)b * NN + qi) * 3;
    const float2 sm = *(const float2*)&smask[((size_t)b * NN + qi) * 2];
    float qpx = qp[0], qpy = qp[1], qpv = qp[2];
    float tpx = tp[0], tpy = tp[1], tpv = tp[2];

    float m0 = 3.4e38f, m1 = 3.4e38f;
#pragma unroll
    for (int k = 0; k < RCH; k++) {
        m0 = fminf(m0, part[((size_t)k * (2 * BB) + b) * NN + qi]);
        m1 = fminf(m1, part[((size_t)k * (2 * BB) + BB + b) * NN + qi]);
    }

    float pvf = (qpv == 1.0f) ? 1.0f : 0.0f;     // pred visible
    float vm  = (tpv == 1.0f) ? 1.0f : 0.0f;     // tgt visible

    float a0 = sqrtf(fmaxf(m0, 1e-12f)) * pvf;   // contrib_p
    float a1 = pvf;                              // cnt_p
    float dx = qpx - tpx, dy = qpy - tpy;
    float e2 = fmaf(dx, dx, dy * dy);
    float tm = fminf(fmaxf(sm.x + sm.y, 0.0f), 1.0f) * vm;
    float a2 = e2 * vm;                          // point sum
    float a3 = e2 * tm;                          // struct sum
    float a4 = tm;                               // mask sum (parity with ref)
    float a5 = sqrtf(fmaxf(m1, 1e-12f)) * vm;    // contrib_t (query = tgt)
    float a6 = vm;                               // cnt_t

    float v[7] = {a0, a1, a2, a3, a4, a5, a6};
    const int wave = tid >> 6, lane = tid & 63;
#pragma unroll
    for (int i = 0; i < 7; i++) {
        float rv = wred(v[i]);
        if (lane == 0) sred[i][wave] = rv;
    }
    __syncthreads();

    if (tid < 64) {
        // Lanes 0-6: one parallel atomicAdd each (single vmem instruction).
        float s = 0.0f;
        if (tid < 7)
            s = sred[tid][0] + sred[tid][1] + sred[tid][2] + sred[tid][3];
        if (tid < 7)
            atomicAdd(&bacc[b * 7 + tid], s);

        // Release: all 7 sum-atomics of this wave complete before the ticket.
        asm volatile("s_waitcnt vmcnt(0)" ::: "memory");

        int old = 0;
        if (tid == 0) old = atomicAdd(&cnt[b], 1);
        old = __shfl(old, 0, 64);

        if (old == 7) {
            // Last block for batch b: all 8 chunk-blocks' sums are complete.
            float t = 0.0f;
            if (tid < 7)
                t = atomicAdd(&bacc[b * 7 + tid], 0.0f);   // coherent parallel read
            float sp  = __shfl(t, 0, 64);
            float cp  = __shfl(t, 1, 64);
            float spt = __shfl(t, 2, 64);
            float sst = __shfl(t, 3, 64);
            float st_ = __shfl(t, 5, 64);
            float ct  = __shfl(t, 6, 64);
            if (tid == 0) {
                float mp = sp / fmaxf(cp, 1.0f);
                float mt = st_ / fmaxf(ct, 1.0f);
                float ch = (cp > 0.0f && ct > 0.0f) ? 0.5f * (mp + mt) : 0.0f;

                const float denom = (float)BB * (float)NN * 2.0f;
                float lp = spt / denom;          // loss_point contribution (batch b)
                float ls = sst / denom;          // loss_struct contribution
                float lc = ch / (float)BB;       // loss_chamfer contribution

                atomicAdd(&out[0], lp + 5.0f * lc + 2.0f * ls);
                atomicAdd(&out[1], lp);
                atomicAdd(&out[3], lc);
                // out[2] stays 0 (zeroed by k1)
            }
        }
    }
}

extern "C" void kernel_launch(void* const* d_in, const int* in_sizes, int n_in,
                              void* d_out, int out_size, void* d_ws, size_t ws_size,
                              hipStream_t stream)
{
    const float* pred  = (const float*)d_in[0];
    const float* tgt   = (const float*)d_in[1];
    const float* smask = (const float*)d_in[2];
    float* out = (float*)d_out;
    float* part = (float*)d_ws;                                          // 8 MB
    float* bacc = (float*)((char*)d_ws + (size_t)RCH * 2 * BB * NN * 4); // 896 B
    int*   cnt  = (int*)(bacc + BB * 7);                                 // 128 B

    k1_chamfer<<<dim3(1, BB, 2 * RCH), TB, 0, stream>>>(pred, tgt, part, (int*)bacc, out);
    k2_final<<<dim3(NN / TB, BB), TB, 0, stream>>>(pred, tgt, smask, part, bacc, cnt, out);
}